// Round 11
// baseline (168.193 us; speedup 1.0000x reference)
//
#include <hip/hip_runtime.h>

// ---------------------------------------------------------------------------
// Causal self-attention block, B=1 T=4096 C=768 H=12 D=64, fp32 in/out.
// bf16 MFMA everywhere; flash attention without online max (scores bounded,
// log2-domain) -> s-chunks combine by pure summation (NO atomics: R4/R5
// showed fp32 atomicAdd accumulation is nondeterministically wrong here;
// exclusive-slot partials are deterministic, proven R6/R7).
// R11: attn staging widened to 128 s-cols per barrier pair (two 64-col
// compute halves per staged tile) -> barrier drains halved per unit work,
// mirroring R10's proven BK=64 GEMM win. LDS 34.8->50 KB (4->3 blocks/CU).
// Chunk accounting in 128-col units (n = qt+1); combine validity updated
// in lockstep. FP add order unchanged -> output bitwise identical to R10.
// ---------------------------------------------------------------------------

#define T_SEQ 4096
#define C_EMB 768
#define NH    12
#define HD    64

typedef __attribute__((ext_vector_type(8))) short bf16x8;   // 8 bf16 = 4 VGPRs
typedef __attribute__((ext_vector_type(4))) float floatx4;  // MFMA C/D

// 0.125 (1/sqrt(64)) * log2(e): folded into Q so scores are log2-domain.
#define QSCALE 0.18033688011112042f

__device__ __forceinline__ unsigned short f2bf(float f) {
  union { float f; unsigned u; } v; v.f = f;
  unsigned r = v.u + 0x7fffu + ((v.u >> 16) & 1u);  // RNE
  return (unsigned short)(r >> 16);
}
// round-half-up, valid for f >= 0 (used for P probabilities)
__device__ __forceinline__ unsigned short f2bf_rhu(float f) {
  union { float f; unsigned u; } v; v.f = f;
  return (unsigned short)((v.u + 0x8000u) >> 16);
}
__device__ __forceinline__ float bf2f(unsigned short h) {
  union { unsigned u; float f; } v; v.u = ((unsigned)h) << 16;
  return v.f;
}

// async global->LDS, 16B/lane. LDS dest is wave-uniform base + lane*16.
__device__ __forceinline__ void gload_lds16(const void* gptr, void* ldsptr) {
  __builtin_amdgcn_global_load_lds(
      (const __attribute__((address_space(1))) unsigned int*)gptr,
      (__attribute__((address_space(3))) unsigned int*)ldsptr,
      16, 0, 0);
}

// ---------------------------------------------------------------------------
// Single fused cast (known-good): [x|wq|wk|wv|wo] fp32 -> contiguous bf16.
// ---------------------------------------------------------------------------
__global__ void cast_all_kernel(const float* __restrict__ x,
                                const float* __restrict__ wq,
                                const float* __restrict__ wk,
                                const float* __restrict__ wv,
                                const float* __restrict__ wo,
                                unsigned short* __restrict__ dst) {
  const int GX = (T_SEQ * C_EMB) / 4;
  const int GW = (C_EMB * C_EMB) / 4;
  int i = blockIdx.x * blockDim.x + threadIdx.x;
  const float* src; int local;
  if (i < GX) { src = x; local = i; }
  else {
    int t = i - GX; int w = t / GW; local = t - w * GW;
    src = (w == 0) ? wq : (w == 1) ? wk : (w == 2) ? wv : wo;
  }
  float4 f = reinterpret_cast<const float4*>(src)[local];
  ushort4 u;
  u.x = f2bf(f.x); u.y = f2bf(f.y); u.z = f2bf(f.z); u.w = f2bf(f.w);
  reinterpret_cast<ushort4*>(dst)[i] = u;
}

// ---------------------------------------------------------------------------
// QKV GEMM, 64x128 tile, BK=64 (R10, proven): C[m][n] = sum_k X[m][k]*W[n][k]
// ---------------------------------------------------------------------------
__global__ __launch_bounds__(256) void gemm_qkv(
    const unsigned short* __restrict__ A,
    const unsigned short* __restrict__ B,
    unsigned short* __restrict__ Qb,
    unsigned short* __restrict__ Kb,
    unsigned short* __restrict__ Vt) {
  constexpr int K = 768, BM = 64, BN = 128, BK = 64;
  __shared__ __align__(16) unsigned short As[BM * BK];   // 8 KB
  __shared__ __align__(16) unsigned short Bs[BN * BK];   // 16 KB
  const int tid = threadIdx.x;
  const int wave = tid >> 6, lane = tid & 63;
  const int lm = lane & 15, lq = lane >> 4;
  const int swz = lm & 7;
  const int m0 = blockIdx.x * BM, n0 = blockIdx.y * BN;
  const int wm = (wave & 1) * 32, wn = (wave >> 1) * 64;
  floatx4 acc[2][4] = {};

  for (int k0 = 0; k0 < K; k0 += BK) {
#pragma unroll
    for (int i = 0; i < 2; i++) {             // A: 512 chunks (64 rows x 8)
      int idx = i * 256 + tid;
      int row = idx >> 3;
      int ch = (idx & 7) ^ (row & 7);
      gload_lds16(A + (size_t)(m0 + row) * K + k0 + ch * 8, (char*)As + idx * 16);
    }
#pragma unroll
    for (int i = 0; i < 4; i++) {             // B: 1024 chunks (128 rows x 8)
      int idx = i * 256 + tid;
      int row = idx >> 3;
      int ch = (idx & 7) ^ (row & 7);
      gload_lds16(B + (size_t)(n0 + row) * K + k0 + ch * 8, (char*)Bs + idx * 16);
    }
    __syncthreads();
#pragma unroll
    for (int kk = 0; kk < 2; kk++) {
      bf16x8 af[2], bfr[4];
#pragma unroll
      for (int i = 0; i < 2; i++) {
        int row = wm + i * 16 + lm;
        af[i] = *(const bf16x8*)(As + row * BK + (((kk * 4 + lq) ^ swz) * 8));
      }
#pragma unroll
      for (int j = 0; j < 4; j++) {
        int row = wn + j * 16 + lm;
        bfr[j] = *(const bf16x8*)(Bs + row * BK + (((kk * 4 + lq) ^ swz) * 8));
      }
#pragma unroll
      for (int i = 0; i < 2; i++)
#pragma unroll
        for (int j = 0; j < 4; j++)
          acc[i][j] = __builtin_amdgcn_mfma_f32_16x16x32_bf16(af[i], bfr[j], acc[i][j], 0, 0, 0);
    }
    __syncthreads();
  }

  const int which = n0 / C_EMB;                   // block-uniform (128 | 768)
  if (which < 2) {
    unsigned short* tgt = (which == 0) ? Qb : Kb;
    const float sc = (which == 0) ? QSCALE : 1.0f;
#pragma unroll
    for (int i = 0; i < 2; i++)
#pragma unroll
      for (int j = 0; j < 4; j++) {
        int n = n0 - which * C_EMB + wn + j * 16 + lm;
        int h = n >> 6, d = n & 63;
#pragma unroll
        for (int r = 0; r < 4; r++) {
          int m = m0 + wm + i * 16 + lq * 4 + r;
          tgt[(((size_t)h * T_SEQ + m) << 6) + d] = f2bf(acc[i][j][r] * sc);
        }
      }
  } else {
#pragma unroll
    for (int i = 0; i < 2; i++)
#pragma unroll
      for (int j = 0; j < 4; j++) {
        int n = n0 - 2 * C_EMB + wn + j * 16 + lm;
        int h = n >> 6, d = n & 63;
        int m = m0 + wm + i * 16 + lq * 4;
        ushort4 pk;
        pk.x = f2bf(acc[i][j][0]); pk.y = f2bf(acc[i][j][1]);
        pk.z = f2bf(acc[i][j][2]); pk.w = f2bf(acc[i][j][3]);
        *(ushort4*)(Vt + ((size_t)(h * HD + d)) * T_SEQ + m) = pk;
      }
  }
}

// ---------------------------------------------------------------------------
// Shared attention inner body (R11): s-steps are 128-col units [sb, se).
// Each staged 128-tile is computed as two 64-col halves; Pw (per-wave) is
// reused across halves (same-wave RW, no barrier). FP order identical to
// the 64-col-step version.
// ---------------------------------------------------------------------------
struct AttnState {
  float rsum[2][4];
  floatx4 o_acc[2][4];
};

template <typename EpilogueFn>
__device__ __forceinline__ void attn_body(
    const unsigned short* __restrict__ Q,
    const unsigned short* __restrict__ K,
    const unsigned short* __restrict__ Vt,
    int h, int q0, int sb, int se,
    unsigned short* Ks, unsigned short* Vs, unsigned short* Ps,
    EpilogueFn epi) {
  constexpr int BS = 128, PS = 72;
  const int tid = threadIdx.x;
  const int wave = tid >> 6, lane = tid & 63;
  const int lm = lane & 15, lq = lane >> 4;
  const unsigned short* Qh = Q + (size_t)h * T_SEQ * HD;
  const unsigned short* Kh = K + (size_t)h * T_SEQ * HD;
  const unsigned short* Vh = Vt + (size_t)h * HD * T_SEQ;
  const int qrow_base = q0 + wave * 32;
  unsigned short* Pw = Ps + wave * 32 * PS;
  const int swz = lm & 7;

  bf16x8 qf[2][2];
#pragma unroll
  for (int m = 0; m < 2; m++)
#pragma unroll
    for (int kk = 0; kk < 2; kk++)
      qf[m][kk] = *(const bf16x8*)(Qh + (size_t)(qrow_base + m * 16 + lm) * HD + kk * 32 + lq * 8);

  AttnState st;
#pragma unroll
  for (int m = 0; m < 2; m++)
#pragma unroll
    for (int r = 0; r < 4; r++) { st.rsum[m][r] = 0.f; st.o_acc[m][r] = floatx4{0.f,0.f,0.f,0.f}; }

  // stage one 128-col tile: K 128x64 (8 chunks/row, key row&7),
  // V 64x128 (16 chunks/row, key row&15).
  auto stage = [&](int s0) {
#pragma unroll
    for (int i = 0; i < 4; i++) {
      int idx = (wave * 4 + i) * 64 + lane;   // 0..1023
      int row = idx >> 3;                     // s-row 0..127
      int ch = (idx & 7) ^ (row & 7);
      gload_lds16(Kh + (size_t)(s0 + row) * HD + ch * 8, (char*)Ks + idx * 16);
    }
#pragma unroll
    for (int i = 0; i < 4; i++) {
      int idx = (wave * 4 + i) * 64 + lane;   // 0..1023
      int row = idx >> 4;                     // d-row 0..63
      int ch = (idx & 15) ^ (row & 15);
      gload_lds16(Vh + (size_t)row * T_SEQ + s0 + ch * 8, (char*)Vs + idx * 16);
    }
  };

  stage(sb * BS);
  for (int it = sb; it < se; ++it) {
    const int s0 = it * BS;
    __syncthreads();                        // staging for this 128-tile done

#pragma unroll
    for (int hb = 0; hb < 2; hb++) {        // two 64-col halves
      const int sh0 = s0 + hb * 64;

      floatx4 sa[2][4] = {};
#pragma unroll
      for (int kk = 0; kk < 2; kk++)
#pragma unroll
        for (int j = 0; j < 4; j++) {
          int row = hb * 64 + j * 16 + lm;  // row&7 == lm&7 == swz
          bf16x8 kf = *(const bf16x8*)(Ks + (row * 8 + ((kk * 4 + lq) ^ swz)) * 8);
#pragma unroll
          for (int m = 0; m < 2; m++)
            sa[m][j] = __builtin_amdgcn_mfma_f32_16x16x32_bf16(qf[m][kk], kf, sa[m][j], 0, 0, 0);
        }

      if (sh0 >= q0 - 64) {                 // diagonal 128-tile: causal mask
#pragma unroll
        for (int m = 0; m < 2; m++)
#pragma unroll
          for (int j = 0; j < 4; j++) {
            int scol = sh0 + j * 16 + lm;
#pragma unroll
            for (int r = 0; r < 4; r++) {
              int qrow = qrow_base + m * 16 + lq * 4 + r;
              if (scol > qrow) sa[m][j][r] = -1e30f;
            }
          }
      }

#pragma unroll
      for (int m = 0; m < 2; m++)
#pragma unroll
        for (int j = 0; j < 4; j++)
#pragma unroll
          for (int r = 0; r < 4; r++) {
            float p = __builtin_amdgcn_exp2f(sa[m][j][r]);
            st.rsum[m][r] += p;
            Pw[(m * 16 + lq * 4 + r) * PS + j * 16 + lm] = f2bf_rhu(p);
          }

#pragma unroll
      for (int kk = 0; kk < 2; kk++) {
        bf16x8 pf[2];
#pragma unroll
        for (int m = 0; m < 2; m++)
          pf[m] = *(const bf16x8*)(Pw + (m * 16 + lm) * PS + kk * 32 + lq * 8);
#pragma unroll
        for (int jd = 0; jd < 4; jd++) {
          int row = jd * 16 + lm;           // row&15 == lm
          bf16x8 vf = *(const bf16x8*)(Vs + (row * 16 + ((hb * 8 + kk * 4 + lq) ^ lm)) * 8);
#pragma unroll
          for (int m = 0; m < 2; m++)
            st.o_acc[m][jd] = __builtin_amdgcn_mfma_f32_16x16x32_bf16(pf[m], vf, st.o_acc[m][jd], 0, 0, 0);
        }
      }
    }

    if (it + 1 < se) {                      // overwrite-safe, then prefetch
      __syncthreads();
      stage(s0 + BS);
    }
  }

  // final row-sum reduction over the 16 lm lanes
#pragma unroll
  for (int m = 0; m < 2; m++)
#pragma unroll
    for (int r = 0; r < 4; r++) {
      float s = st.rsum[m][r];
      s += __shfl_xor(s, 1);
      s += __shfl_xor(s, 2);
      s += __shfl_xor(s, 4);
      s += __shfl_xor(s, 8);
      st.rsum[m][r] = s;
    }
  epi(st, qrow_base, lm, lq);
}

// ---------------------------------------------------------------------------
// Path B (fallback for small ws): 2 chunks (128-col units), bf16 partials.
// ---------------------------------------------------------------------------
__global__ __launch_bounds__(256, 3) void attn_kernel2(
    const unsigned short* __restrict__ Q,
    const unsigned short* __restrict__ K,
    const unsigned short* __restrict__ Vt,
    unsigned short* __restrict__ Op0,
    unsigned short* __restrict__ Op1,
    float* __restrict__ lpart) {
  constexpr int PS = 72;
  __shared__ __align__(16) unsigned short Ks[128 * HD];
  __shared__ __align__(16) unsigned short Vs[HD * 128];
  __shared__ __align__(16) unsigned short Ps[4 * 32 * PS];
  const int bid = blockIdx.x;               // 0..767
  const int h = bid % NH;
  const int z = bid / NH;
  const int qt = (T_SEQ / 128 - 1) - (z >> 1);
  const int c = z & 1;
  const int q0 = qt * 128;
  const int n = qt + 1;                     // 128-col steps for this tile
  const int sb = (n * c) >> 1, se = (n * (c + 1)) >> 1;
  if (sb == se) return;                     // empty chunk (block-uniform exit)

  unsigned short* Oc = c ? Op1 : Op0;
  float* lc = lpart + (size_t)c * NH * T_SEQ;
  attn_body(Q, K, Vt, h, q0, sb, se, Ks, Vs, Ps,
    [&](const AttnState& st, int qrow_base, int lm, int lq) {
#pragma unroll
      for (int m = 0; m < 2; m++)
#pragma unroll
        for (int r = 0; r < 4; r++) {
          int t = qrow_base + m * 16 + lq * 4 + r;
          if (lm == 0) lc[h * T_SEQ + t] = st.rsum[m][r];
#pragma unroll
          for (int jd = 0; jd < 4; jd++)
            Oc[((size_t)h * T_SEQ + t) * HD + jd * 16 + lm] = f2bf(st.o_acc[m][jd][r]);
        }
    });
}

__global__ void combine_kernel2(const unsigned short* __restrict__ Op0,
                                const unsigned short* __restrict__ Op1,
                                const float* __restrict__ lpart,
                                unsigned short* __restrict__ Ob) {
  int idx = blockIdx.x * blockDim.x + threadIdx.x;
  int d4 = idx & 15;
  int t = (idx >> 4) & (T_SEQ - 1);
  int h = idx >> 16;
  const int qt = t >> 7;
  const int n = qt + 1;
  float o[4] = {0.f, 0.f, 0.f, 0.f};
  float l = 0.f;
#pragma unroll
  for (int c = 0; c < 2; c++) {
    if (((n * c) >> 1) != ((n * (c + 1)) >> 1)) {   // chunk non-empty
      ushort4 a = reinterpret_cast<const ushort4*>(c ? Op1 : Op0)[idx];
      o[0] += bf2f(a.x); o[1] += bf2f(a.y); o[2] += bf2f(a.z); o[3] += bf2f(a.w);
      l += lpart[c * NH * T_SEQ + h * T_SEQ + t];
    }
  }
  float inv = 1.0f / l;
  ushort4 u;
  u.x = f2bf(o[0] * inv); u.y = f2bf(o[1] * inv);
  u.z = f2bf(o[2] * inv); u.w = f2bf(o[3] * inv);
  *(ushort4*)(Ob + (size_t)t * C_EMB + h * HD + d4 * 4) = u;
}

// ---------------------------------------------------------------------------
// Path A (proven R7 structure, 128-col steps): 4 chunks, fp32 partials.
// ---------------------------------------------------------------------------
__global__ __launch_bounds__(256, 3) void attn_kernel4(
    const unsigned short* __restrict__ Q,
    const unsigned short* __restrict__ K,
    const unsigned short* __restrict__ Vt,
    float* __restrict__ Opart,              // [4][12][4096][64] fp32
    float* __restrict__ lpart) {            // [4][12][4096] fp32
  constexpr int PS = 72;
  __shared__ __align__(16) unsigned short Ks[128 * HD];
  __shared__ __align__(16) unsigned short Vs[HD * 128];
  __shared__ __align__(16) unsigned short Ps[4 * 32 * PS];
  const int bid = blockIdx.x;               // 0..1535
  const int h = bid % NH;
  const int z = bid / NH;                   // 0..127
  const int qt = (T_SEQ / 128 - 1) - (z >> 2);  // heavy tiles first
  const int c = z & 3;
  const int q0 = qt * 128;
  const int n = qt + 1;                     // 128-col steps for this tile
  const int sb = (n * c) >> 2, se = (n * (c + 1)) >> 2;
  if (sb == se) return;                     // empty chunk (block-uniform exit)

  const size_t CN = (size_t)NH * T_SEQ * HD;
  float* Oc = Opart + (size_t)c * CN;
  float* lc = lpart + (size_t)c * NH * T_SEQ;
  attn_body(Q, K, Vt, h, q0, sb, se, Ks, Vs, Ps,
    [&](const AttnState& st, int qrow_base, int lm, int lq) {
#pragma unroll
      for (int m = 0; m < 2; m++)
#pragma unroll
        for (int r = 0; r < 4; r++) {
          int t = qrow_base + m * 16 + lq * 4 + r;
          if (lm == 0) lc[h * T_SEQ + t] = st.rsum[m][r];
#pragma unroll
          for (int jd = 0; jd < 4; jd++)
            Oc[((size_t)h * T_SEQ + t) * HD + jd * 16 + lm] = st.o_acc[m][jd][r];
        }
    });
}

__global__ void combine_kernel4(const float* __restrict__ Opart,
                                const float* __restrict__ lpart,
                                unsigned short* __restrict__ Ob) {
  int idx = blockIdx.x * blockDim.x + threadIdx.x;  // float4 groups
  int d4 = idx & 15;
  int t = (idx >> 4) & (T_SEQ - 1);
  int h = idx >> 16;
  const int qt = t >> 7;
  const int n = qt + 1;                     // 128-col units (matches attn4)
  const size_t CN4 = (size_t)NH * T_SEQ * HD / 4;
  float4 o = make_float4(0.f, 0.f, 0.f, 0.f);
  float l = 0.f;
#pragma unroll
  for (int c = 0; c < 4; c++) {
    if (((n * c) >> 2) != ((n * (c + 1)) >> 2)) {   // chunk non-empty
      float4 p = reinterpret_cast<const float4*>(Opart)[c * CN4 + idx];
      o.x += p.x; o.y += p.y; o.z += p.z; o.w += p.w;
      l += lpart[c * NH * T_SEQ + h * T_SEQ + t];
    }
  }
  float inv = 1.0f / l;
  ushort4 u;
  u.x = f2bf(o.x * inv); u.y = f2bf(o.y * inv);
  u.z = f2bf(o.z * inv); u.w = f2bf(o.w * inv);
  *(ushort4*)(Ob + (size_t)t * C_EMB + h * HD + d4 * 4) = u;
}

// ---------------------------------------------------------------------------
// Output GEMM, 64x128 tile, BK=64 (R10, proven): fp32 out.
// ---------------------------------------------------------------------------
__global__ __launch_bounds__(256) void gemm_out(
    const unsigned short* __restrict__ A,
    const unsigned short* __restrict__ B,
    float* __restrict__ Out) {
  constexpr int K = 768, BM = 64, BN = 128, BK = 64;
  __shared__ __align__(16) unsigned short As[BM * BK];   // 8 KB
  __shared__ __align__(16) unsigned short Bs[BN * BK];   // 16 KB
  const int tid = threadIdx.x;
  const int wave = tid >> 6, lane = tid & 63;
  const int lm = lane & 15, lq = lane >> 4;
  const int swz = lm & 7;
  const int m0 = blockIdx.x * BM, n0 = blockIdx.y * BN;
  const int wm = (wave & 1) * 32, wn = (wave >> 1) * 64;
  floatx4 acc[2][4] = {};

  for (int k0 = 0; k0 < K; k0 += BK) {
#pragma unroll
    for (int i = 0; i < 2; i++) {
      int idx = i * 256 + tid;
      int row = idx >> 3;
      int ch = (idx & 7) ^ (row & 7);
      gload_lds16(A + (size_t)(m0 + row) * K + k0 + ch * 8, (char*)As + idx * 16);
    }
#pragma unroll
    for (int i = 0; i < 4; i++) {
      int idx = i * 256 + tid;
      int row = idx >> 3;
      int ch = (idx & 7) ^ (row & 7);
      gload_lds16(B + (size_t)(n0 + row) * K + k0 + ch * 8, (char*)Bs + idx * 16);
    }
    __syncthreads();
#pragma unroll
    for (int kk = 0; kk < 2; kk++) {
      bf16x8 af[2], bfr[4];
#pragma unroll
      for (int i = 0; i < 2; i++) {
        int row = wm + i * 16 + lm;
        af[i] = *(const bf16x8*)(As + row * BK + (((kk * 4 + lq) ^ swz) * 8));
      }
#pragma unroll
      for (int j = 0; j < 4; j++) {
        int row = wn + j * 16 + lm;
        bfr[j] = *(const bf16x8*)(Bs + row * BK + (((kk * 4 + lq) ^ swz) * 8));
      }
#pragma unroll
      for (int i = 0; i < 2; i++)
#pragma unroll
        for (int j = 0; j < 4; j++)
          acc[i][j] = __builtin_amdgcn_mfma_f32_16x16x32_bf16(af[i], bfr[j], acc[i][j], 0, 0, 0);
    }
    __syncthreads();
  }
#pragma unroll
  for (int i = 0; i < 2; i++)
#pragma unroll
    for (int j = 0; j < 4; j++)
#pragma unroll
      for (int r = 0; r < 4; r++) {
        int m = m0 + wm + i * 16 + lq * 4 + r;
        int n = n0 + wn + j * 16 + lm;
        Out[(size_t)m * C_EMB + n] = acc[i][j][r];
      }
}

// ---------------------------------------------------------------------------
// Workspace layouts (unchanged from R7-R10).
// Head (shorts): Xb[0,XN) | Wqkv[XN,XN+3WN) | Wob | Qb->Ob | Kb | Vt | tail.
// Path A (>= 81,002,496 B): fp32 Opart4+lpart4 in tail.
// Path B: Op0=dead Xb, lpart=dead Wqkv, Op1=tail (bf16). 36.18 MB total.
// ---------------------------------------------------------------------------
extern "C" void kernel_launch(void* const* d_in, const int* in_sizes, int n_in,
                              void* d_out, int out_size, void* d_ws, size_t ws_size,
                              hipStream_t stream) {
  const float* x  = (const float*)d_in[0];
  const float* wq = (const float*)d_in[1];
  const float* wk = (const float*)d_in[2];
  const float* wv = (const float*)d_in[3];
  const float* wo = (const float*)d_in[4];
  float* out = (float*)d_out;

  const size_t XN = (size_t)T_SEQ * C_EMB;      // 3,145,728 elems
  const size_t WN = (size_t)C_EMB * C_EMB;      //   589,824 elems
  unsigned short* base = (unsigned short*)d_ws;

  unsigned short* Xb   = base;
  unsigned short* Wqkv = base + XN;
  unsigned short* Wob  = base + XN + 3 * WN;
  unsigned short* Qb   = base + XN + 4 * WN;
  unsigned short* Kb   = Qb + XN;
  unsigned short* Vt   = Kb + XN;
  unsigned short* tail = Vt + XN;               // byte 29,884,416
  unsigned short* Ob   = Qb;                    // alias: Q dead after attn

  const size_t needA = 29884416ull + 4ull * XN * 4ull + 4ull * NH * T_SEQ * 4ull;  // 81,002,496

  const int ngroups = (int)((XN + 4 * WN) / 4); // 1,376,256
  cast_all_kernel<<<dim3(ngroups / 256), 256, 0, stream>>>(x, wq, wk, wv, wo, Xb);

  gemm_qkv<<<dim3(T_SEQ / 64, 2304 / 128), 256, 0, stream>>>(Xb, Wqkv, Qb, Kb, Vt);

  if (ws_size >= needA) {
    float* Opart4 = (float*)tail;
    float* lpart4 = Opart4 + 4 * XN;
    attn_kernel4<<<dim3((T_SEQ / 128) * 4 * NH), 256, 0, stream>>>(Qb, Kb, Vt, Opart4, lpart4);
    combine_kernel4<<<dim3((int)(XN / 4) / 256), 256, 0, stream>>>(Opart4, lpart4, Ob);
  } else {
    unsigned short* Op0 = base;
    unsigned short* Op1 = tail;
    float* lpart = (float*)(base + XN);
    attn_kernel2<<<dim3((T_SEQ / 128) * 2 * NH), 256, 0, stream>>>(Qb, Kb, Vt, Op0, Op1, lpart);
    combine_kernel2<<<dim3((int)(XN / 4) / 256), 256, 0, stream>>>(Op0, Op1, lpart, Ob);
  }

  gemm_out<<<dim3(T_SEQ / 64, C_EMB / 128), 256, 0, stream>>>(Ob, Wob, out);
}

// Round 14
// 167.417 us; speedup vs baseline: 1.0046x; 1.0046x over previous
//
#include <hip/hip_runtime.h>

// ---------------------------------------------------------------------------
// Causal self-attention block, B=1 T=4096 C=768 H=12 D=64, fp32 in/out.
// bf16 MFMA everywhere; flash attention without online max (scores bounded,
// log2-domain) -> s-chunks combine by pure summation (NO atomics; exclusive-
// slot partials, proven R6/R7).
// R14: transposed-S ABANDONED (R9/R12/R13: three distinct failures, no
// provable root cause). Base = R10 (166.7 us, proven). One change: m-split
// P-buffer -- the two M-fragments time-share one 16-row per-wave P buffer
// (write P[m] -> PV[m] -> reuse for m+1; all same-wave in-order LDS, the
// exact ordering R10 already relies on). Ps 18.4->9.2 KB, LDS block
// 34,816->25,600 B -> 6 blocks/CU (was 4). FP order unchanged -> output
// bitwise identical to R10. Cost: vf re-read per m (+8 ds_read_b128/step).
// ---------------------------------------------------------------------------

#define T_SEQ 4096
#define C_EMB 768
#define NH    12
#define HD    64

typedef __attribute__((ext_vector_type(8))) short bf16x8;   // 8 bf16 = 4 VGPRs
typedef __attribute__((ext_vector_type(4))) float floatx4;  // MFMA C/D

// 0.125 (1/sqrt(64)) * log2(e): folded into Q so scores are log2-domain.
#define QSCALE 0.18033688011112042f

__device__ __forceinline__ unsigned short f2bf(float f) {
  union { float f; unsigned u; } v; v.f = f;
  unsigned r = v.u + 0x7fffu + ((v.u >> 16) & 1u);  // RNE
  return (unsigned short)(r >> 16);
}
// round-half-up, valid for f >= 0 (used for P probabilities)
__device__ __forceinline__ unsigned short f2bf_rhu(float f) {
  union { float f; unsigned u; } v; v.f = f;
  return (unsigned short)((v.u + 0x8000u) >> 16);
}
__device__ __forceinline__ float bf2f(unsigned short h) {
  union { unsigned u; float f; } v; v.u = ((unsigned)h) << 16;
  return v.f;
}

// async global->LDS, 16B/lane. LDS dest is wave-uniform base + lane*16.
__device__ __forceinline__ void gload_lds16(const void* gptr, void* ldsptr) {
  __builtin_amdgcn_global_load_lds(
      (const __attribute__((address_space(1))) unsigned int*)gptr,
      (__attribute__((address_space(3))) unsigned int*)ldsptr,
      16, 0, 0);
}

// ---------------------------------------------------------------------------
// Single fused cast (known-good): [x|wq|wk|wv|wo] fp32 -> contiguous bf16.
// ---------------------------------------------------------------------------
__global__ void cast_all_kernel(const float* __restrict__ x,
                                const float* __restrict__ wq,
                                const float* __restrict__ wk,
                                const float* __restrict__ wv,
                                const float* __restrict__ wo,
                                unsigned short* __restrict__ dst) {
  const int GX = (T_SEQ * C_EMB) / 4;
  const int GW = (C_EMB * C_EMB) / 4;
  int i = blockIdx.x * blockDim.x + threadIdx.x;
  const float* src; int local;
  if (i < GX) { src = x; local = i; }
  else {
    int t = i - GX; int w = t / GW; local = t - w * GW;
    src = (w == 0) ? wq : (w == 1) ? wk : (w == 2) ? wv : wo;
  }
  float4 f = reinterpret_cast<const float4*>(src)[local];
  ushort4 u;
  u.x = f2bf(f.x); u.y = f2bf(f.y); u.z = f2bf(f.z); u.w = f2bf(f.w);
  reinterpret_cast<ushort4*>(dst)[i] = u;
}

// ---------------------------------------------------------------------------
// QKV GEMM, 64x128 tile, BK=64 (R10, proven): C[m][n] = sum_k X[m][k]*W[n][k]
// ---------------------------------------------------------------------------
__global__ __launch_bounds__(256) void gemm_qkv(
    const unsigned short* __restrict__ A,
    const unsigned short* __restrict__ B,
    unsigned short* __restrict__ Qb,
    unsigned short* __restrict__ Kb,
    unsigned short* __restrict__ Vt) {
  constexpr int K = 768, BM = 64, BN = 128, BK = 64;
  __shared__ __align__(16) unsigned short As[BM * BK];   // 8 KB
  __shared__ __align__(16) unsigned short Bs[BN * BK];   // 16 KB
  const int tid = threadIdx.x;
  const int wave = tid >> 6, lane = tid & 63;
  const int lm = lane & 15, lq = lane >> 4;
  const int swz = lm & 7;
  const int m0 = blockIdx.x * BM, n0 = blockIdx.y * BN;
  const int wm = (wave & 1) * 32, wn = (wave >> 1) * 64;
  floatx4 acc[2][4] = {};

  for (int k0 = 0; k0 < K; k0 += BK) {
#pragma unroll
    for (int i = 0; i < 2; i++) {             // A: 512 chunks (64 rows x 8)
      int idx = i * 256 + tid;
      int row = idx >> 3;
      int ch = (idx & 7) ^ (row & 7);
      gload_lds16(A + (size_t)(m0 + row) * K + k0 + ch * 8, (char*)As + idx * 16);
    }
#pragma unroll
    for (int i = 0; i < 4; i++) {             // B: 1024 chunks (128 rows x 8)
      int idx = i * 256 + tid;
      int row = idx >> 3;
      int ch = (idx & 7) ^ (row & 7);
      gload_lds16(B + (size_t)(n0 + row) * K + k0 + ch * 8, (char*)Bs + idx * 16);
    }
    __syncthreads();
#pragma unroll
    for (int kk = 0; kk < 2; kk++) {
      bf16x8 af[2], bfr[4];
#pragma unroll
      for (int i = 0; i < 2; i++) {
        int row = wm + i * 16 + lm;
        af[i] = *(const bf16x8*)(As + row * BK + (((kk * 4 + lq) ^ swz) * 8));
      }
#pragma unroll
      for (int j = 0; j < 4; j++) {
        int row = wn + j * 16 + lm;
        bfr[j] = *(const bf16x8*)(Bs + row * BK + (((kk * 4 + lq) ^ swz) * 8));
      }
#pragma unroll
      for (int i = 0; i < 2; i++)
#pragma unroll
        for (int j = 0; j < 4; j++)
          acc[i][j] = __builtin_amdgcn_mfma_f32_16x16x32_bf16(af[i], bfr[j], acc[i][j], 0, 0, 0);
    }
    __syncthreads();
  }

  const int which = n0 / C_EMB;                   // block-uniform (128 | 768)
  if (which < 2) {
    unsigned short* tgt = (which == 0) ? Qb : Kb;
    const float sc = (which == 0) ? QSCALE : 1.0f;
#pragma unroll
    for (int i = 0; i < 2; i++)
#pragma unroll
      for (int j = 0; j < 4; j++) {
        int n = n0 - which * C_EMB + wn + j * 16 + lm;
        int h = n >> 6, d = n & 63;
#pragma unroll
        for (int r = 0; r < 4; r++) {
          int m = m0 + wm + i * 16 + lq * 4 + r;
          tgt[(((size_t)h * T_SEQ + m) << 6) + d] = f2bf(acc[i][j][r] * sc);
        }
      }
  } else {
#pragma unroll
    for (int i = 0; i < 2; i++)
#pragma unroll
      for (int j = 0; j < 4; j++) {
        int n = n0 - 2 * C_EMB + wn + j * 16 + lm;
        int h = n >> 6, d = n & 63;
        int m = m0 + wm + i * 16 + lq * 4;
        ushort4 pk;
        pk.x = f2bf(acc[i][j][0]); pk.y = f2bf(acc[i][j][1]);
        pk.z = f2bf(acc[i][j][2]); pk.w = f2bf(acc[i][j][3]);
        *(ushort4*)(Vt + ((size_t)(h * HD + d)) * T_SEQ + m) = pk;
      }
  }
}

// ---------------------------------------------------------------------------
// Shared attention inner body (R14 = R10 + m-split P buffer): 64-col s-steps
// [sb, se). Per staged tile: for each M-fragment m, write its 16 P rows to
// the per-wave 16-row buffer, roundtrip to A-fragments, 8 PV MFMAs, then
// reuse the buffer for the next m (same-wave in-order LDS ordering, exactly
// R10's existing dependency pattern). FP order identical to R10.
// ---------------------------------------------------------------------------
struct AttnState {
  float rsum[2][4];
  floatx4 o_acc[2][4];
};

template <typename EpilogueFn>
__device__ __forceinline__ void attn_body(
    const unsigned short* __restrict__ Q,
    const unsigned short* __restrict__ K,
    const unsigned short* __restrict__ Vt,
    int h, int q0, int sb, int se,
    unsigned short* Ks, unsigned short* Vs, unsigned short* Ps,
    EpilogueFn epi) {
  constexpr int BS = 64, PS = 72;
  const int tid = threadIdx.x;
  const int wave = tid >> 6, lane = tid & 63;
  const int lm = lane & 15, lq = lane >> 4;
  const unsigned short* Qh = Q + (size_t)h * T_SEQ * HD;
  const unsigned short* Kh = K + (size_t)h * T_SEQ * HD;
  const unsigned short* Vh = Vt + (size_t)h * HD * T_SEQ;
  const int qrow_base = q0 + wave * 32;
  unsigned short* Pw = Ps + wave * 16 * PS;   // 16-row buffer, time-shared by m
  const int swz = lm & 7;

  bf16x8 qf[2][2];
#pragma unroll
  for (int m = 0; m < 2; m++)
#pragma unroll
    for (int kk = 0; kk < 2; kk++)
      qf[m][kk] = *(const bf16x8*)(Qh + (size_t)(qrow_base + m * 16 + lm) * HD + kk * 32 + lq * 8);

  AttnState st;
#pragma unroll
  for (int m = 0; m < 2; m++)
#pragma unroll
    for (int r = 0; r < 4; r++) { st.rsum[m][r] = 0.f; st.o_acc[m][r] = floatx4{0.f, 0.f, 0.f, 0.f}; }

  auto stage = [&](int s0) {
#pragma unroll
    for (int i = 0; i < 2; i++) {
      int idx = (wave * 2 + i) * 64 + lane;
      int row = idx >> 3;
      int ch = (idx & 7) ^ (row & 7);
      gload_lds16(Kh + (size_t)(s0 + row) * HD + ch * 8, (char*)Ks + idx * 16);
      gload_lds16(Vh + (size_t)row * T_SEQ + s0 + ch * 8, (char*)Vs + idx * 16);
    }
  };

  stage(sb * BS);
  for (int it = sb; it < se; ++it) {
    const int s0 = it * BS;
    __syncthreads();                        // staging for this step complete

    // S = Q K^T (log2 domain; R10 orientation, proven)
    floatx4 sa[2][4] = {};
#pragma unroll
    for (int kk = 0; kk < 2; kk++)
#pragma unroll
      for (int j = 0; j < 4; j++) {
        int row = j * 16 + lm;
        bf16x8 kf = *(const bf16x8*)(Ks + (row * 8 + ((kk * 4 + lq) ^ swz)) * 8);
#pragma unroll
        for (int m = 0; m < 2; m++)
          sa[m][j] = __builtin_amdgcn_mfma_f32_16x16x32_bf16(qf[m][kk], kf, sa[m][j], 0, 0, 0);
      }

    if (s0 >= q0) {                         // diagonal band: causal mask
#pragma unroll
      for (int m = 0; m < 2; m++)
#pragma unroll
        for (int j = 0; j < 4; j++) {
          int scol = s0 + j * 16 + lm;
#pragma unroll
          for (int r = 0; r < 4; r++) {
            int qrow = qrow_base + m * 16 + lq * 4 + r;
            if (scol > qrow) sa[m][j][r] = -1e30f;
          }
        }
    }

    // m-split: write P[m] (16 rows) -> pf roundtrip -> PV[m]; reuse buffer.
#pragma unroll
    for (int m = 0; m < 2; m++) {
#pragma unroll
      for (int j = 0; j < 4; j++)
#pragma unroll
        for (int r = 0; r < 4; r++) {
          float p = __builtin_amdgcn_exp2f(sa[m][j][r]);
          st.rsum[m][r] += p;
          Pw[(lq * 4 + r) * PS + j * 16 + lm] = f2bf_rhu(p);
        }
#pragma unroll
      for (int kk = 0; kk < 2; kk++) {
        bf16x8 pf = *(const bf16x8*)(Pw + lm * PS + kk * 32 + lq * 8);
#pragma unroll
        for (int jd = 0; jd < 4; jd++) {
          int row = jd * 16 + lm;
          bf16x8 vf = *(const bf16x8*)(Vs + (row * 8 + ((kk * 4 + lq) ^ swz)) * 8);
          st.o_acc[m][jd] = __builtin_amdgcn_mfma_f32_16x16x32_bf16(pf, vf, st.o_acc[m][jd], 0, 0, 0);
        }
      }
    }

    if (it + 1 < se) {                      // overwrite-safe, then prefetch
      __syncthreads();
      stage(s0 + BS);
    }
  }

  // final row-sum reduction over the 16 lm lanes (R10, proven)
#pragma unroll
  for (int m = 0; m < 2; m++)
#pragma unroll
    for (int r = 0; r < 4; r++) {
      float s = st.rsum[m][r];
      s += __shfl_xor(s, 1);
      s += __shfl_xor(s, 2);
      s += __shfl_xor(s, 4);
      s += __shfl_xor(s, 8);
      st.rsum[m][r] = s;
    }
  epi(st, qrow_base, lm, lq);
}

// ---------------------------------------------------------------------------
// Path B (fallback for small ws): 2 chunks, bf16 partials.
// ---------------------------------------------------------------------------
__global__ __launch_bounds__(256, 4) void attn_kernel2(
    const unsigned short* __restrict__ Q,
    const unsigned short* __restrict__ K,
    const unsigned short* __restrict__ Vt,
    unsigned short* __restrict__ Op0,
    unsigned short* __restrict__ Op1,
    float* __restrict__ lpart) {
  constexpr int PS = 72;
  __shared__ __align__(16) unsigned short Ks[64 * HD];
  __shared__ __align__(16) unsigned short Vs[HD * 64];
  __shared__ __align__(16) unsigned short Ps[4 * 16 * PS];
  const int bid = blockIdx.x;               // 0..767
  const int h = bid % NH;
  const int z = bid / NH;
  const int qt = (T_SEQ / 128 - 1) - (z >> 1);
  const int c = z & 1;
  const int q0 = qt * 128;
  const int sb = c ? (qt + 1) : 0;
  const int se = c ? (2 * qt + 2) : (qt + 1);

  unsigned short* Oc = c ? Op1 : Op0;
  float* lc = lpart + (size_t)c * NH * T_SEQ;
  attn_body(Q, K, Vt, h, q0, sb, se, Ks, Vs, Ps,
    [&](const AttnState& st, int qrow_base, int lm, int lq) {
#pragma unroll
      for (int m = 0; m < 2; m++)
#pragma unroll
        for (int r = 0; r < 4; r++) {
          int t = qrow_base + m * 16 + lq * 4 + r;
          if (lm == 0) lc[h * T_SEQ + t] = st.rsum[m][r];
#pragma unroll
          for (int jd = 0; jd < 4; jd++)
            Oc[((size_t)h * T_SEQ + t) * HD + jd * 16 + lm] = f2bf(st.o_acc[m][jd][r]);
        }
    });
}

__global__ void combine_kernel2(const unsigned short* __restrict__ Op0,
                                const unsigned short* __restrict__ Op1,
                                const float* __restrict__ lpart,
                                unsigned short* __restrict__ Ob) {
  int idx = blockIdx.x * blockDim.x + threadIdx.x;
  int d4 = idx & 15;
  int t = (idx >> 4) & (T_SEQ - 1);
  int h = idx >> 16;
  float l = lpart[h * T_SEQ + t] + lpart[NH * T_SEQ + h * T_SEQ + t];
  float inv = 1.0f / l;
  ushort4 a = reinterpret_cast<const ushort4*>(Op0)[idx];
  ushort4 b = reinterpret_cast<const ushort4*>(Op1)[idx];
  ushort4 u;
  u.x = f2bf((bf2f(a.x) + bf2f(b.x)) * inv);
  u.y = f2bf((bf2f(a.y) + bf2f(b.y)) * inv);
  u.z = f2bf((bf2f(a.z) + bf2f(b.z)) * inv);
  u.w = f2bf((bf2f(a.w) + bf2f(b.w)) * inv);
  *(ushort4*)(Ob + (size_t)t * C_EMB + h * HD + d4 * 4) = u;
}

// ---------------------------------------------------------------------------
// Path A (R7/R10 structure, proven): 4 chunks, fp32 partials.
// ---------------------------------------------------------------------------
__global__ __launch_bounds__(256, 4) void attn_kernel4(
    const unsigned short* __restrict__ Q,
    const unsigned short* __restrict__ K,
    const unsigned short* __restrict__ Vt,
    float* __restrict__ Opart,              // [4][12][4096][64] fp32
    float* __restrict__ lpart) {            // [4][12][4096] fp32
  constexpr int PS = 72;
  __shared__ __align__(16) unsigned short Ks[64 * HD];
  __shared__ __align__(16) unsigned short Vs[HD * 64];
  __shared__ __align__(16) unsigned short Ps[4 * 16 * PS];
  const int bid = blockIdx.x;               // 0..1535
  const int h = bid % NH;
  const int z = bid / NH;                   // 0..127
  const int qt = (T_SEQ / 128 - 1) - (z >> 2);  // heavy tiles first
  const int c = z & 3;
  const int q0 = qt * 128;
  const int n = 2 * qt + 2;                 // 64-col steps for this tile
  const int sb = (n * c) >> 2, se = (n * (c + 1)) >> 2;
  if (sb == se) return;                     // empty chunk (block-uniform exit)

  const size_t CN = (size_t)NH * T_SEQ * HD;
  float* Oc = Opart + (size_t)c * CN;
  float* lc = lpart + (size_t)c * NH * T_SEQ;
  attn_body(Q, K, Vt, h, q0, sb, se, Ks, Vs, Ps,
    [&](const AttnState& st, int qrow_base, int lm, int lq) {
#pragma unroll
      for (int m = 0; m < 2; m++)
#pragma unroll
        for (int r = 0; r < 4; r++) {
          int t = qrow_base + m * 16 + lq * 4 + r;
          if (lm == 0) lc[h * T_SEQ + t] = st.rsum[m][r];
#pragma unroll
          for (int jd = 0; jd < 4; jd++)
            Oc[((size_t)h * T_SEQ + t) * HD + jd * 16 + lm] = st.o_acc[m][jd][r];
        }
    });
}

__global__ void combine_kernel4(const float* __restrict__ Opart,
                                const float* __restrict__ lpart,
                                unsigned short* __restrict__ Ob) {
  int idx = blockIdx.x * blockDim.x + threadIdx.x;  // float4 groups
  int d4 = idx & 15;
  int t = (idx >> 4) & (T_SEQ - 1);
  int h = idx >> 16;
  const int qt = t >> 7;
  const int n = 2 * qt + 2;                 // 64-col units (matches attn4)
  const size_t CN4 = (size_t)NH * T_SEQ * HD / 4;
  float4 o = make_float4(0.f, 0.f, 0.f, 0.f);
  float l = 0.f;
#pragma unroll
  for (int c = 0; c < 4; c++) {
    if (((n * c) >> 2) != ((n * (c + 1)) >> 2)) {   // chunk non-empty
      float4 p = reinterpret_cast<const float4*>(Opart)[c * CN4 + idx];
      o.x += p.x; o.y += p.y; o.z += p.z; o.w += p.w;
      l += lpart[c * NH * T_SEQ + h * T_SEQ + t];
    }
  }
  float inv = 1.0f / l;
  ushort4 u;
  u.x = f2bf(o.x * inv); u.y = f2bf(o.y * inv);
  u.z = f2bf(o.z * inv); u.w = f2bf(o.w * inv);
  *(ushort4*)(Ob + (size_t)t * C_EMB + h * HD + d4 * 4) = u;
}

// ---------------------------------------------------------------------------
// Output GEMM, 64x128 tile, BK=64 (R10, proven): fp32 out.
// ---------------------------------------------------------------------------
__global__ __launch_bounds__(256) void gemm_out(
    const unsigned short* __restrict__ A,
    const unsigned short* __restrict__ B,
    float* __restrict__ Out) {
  constexpr int K = 768, BM = 64, BN = 128, BK = 64;
  __shared__ __align__(16) unsigned short As[BM * BK];   // 8 KB
  __shared__ __align__(16) unsigned short Bs[BN * BK];   // 16 KB
  const int tid = threadIdx.x;
  const int wave = tid >> 6, lane = tid & 63;
  const int lm = lane & 15, lq = lane >> 4;
  const int swz = lm & 7;
  const int m0 = blockIdx.x * BM, n0 = blockIdx.y * BN;
  const int wm = (wave & 1) * 32, wn = (wave >> 1) * 64;
  floatx4 acc[2][4] = {};

  for (int k0 = 0; k0 < K; k0 += BK) {
#pragma unroll
    for (int i = 0; i < 2; i++) {
      int idx = i * 256 + tid;
      int row = idx >> 3;
      int ch = (idx & 7) ^ (row & 7);
      gload_lds16(A + (size_t)(m0 + row) * K + k0 + ch * 8, (char*)As + idx * 16);
    }
#pragma unroll
    for (int i = 0; i < 4; i++) {
      int idx = i * 256 + tid;
      int row = idx >> 3;
      int ch = (idx & 7) ^ (row & 7);
      gload_lds16(B + (size_t)(n0 + row) * K + k0 + ch * 8, (char*)Bs + idx * 16);
    }
    __syncthreads();
#pragma unroll
    for (int kk = 0; kk < 2; kk++) {
      bf16x8 af[2], bfr[4];
#pragma unroll
      for (int i = 0; i < 2; i++) {
        int row = wm + i * 16 + lm;
        af[i] = *(const bf16x8*)(As + row * BK + (((kk * 4 + lq) ^ swz) * 8));
      }
#pragma unroll
      for (int j = 0; j < 4; j++) {
        int row = wn + j * 16 + lm;
        bfr[j] = *(const bf16x8*)(Bs + row * BK + (((kk * 4 + lq) ^ swz) * 8));
      }
#pragma unroll
      for (int i = 0; i < 2; i++)
#pragma unroll
        for (int j = 0; j < 4; j++)
          acc[i][j] = __builtin_amdgcn_mfma_f32_16x16x32_bf16(af[i], bfr[j], acc[i][j], 0, 0, 0);
    }
    __syncthreads();
  }
#pragma unroll
  for (int i = 0; i < 2; i++)
#pragma unroll
    for (int j = 0; j < 4; j++)
#pragma unroll
      for (int r = 0; r < 4; r++) {
        int m = m0 + wm + i * 16 + lq * 4 + r;
        int n = n0 + wn + j * 16 + lm;
        Out[(size_t)m * C_EMB + n] = acc[i][j][r];
      }
}

// ---------------------------------------------------------------------------
// Workspace layouts (unchanged from R7-R10).
// Head (shorts): Xb[0,XN) | Wqkv[XN,XN+3WN) | Wob | Qb->Ob | Kb | Vt | tail.
// Path A (>= 81,002,496 B): fp32 Opart4+lpart4 in tail.
// Path B: Op0=dead Xb, lpart=dead Wqkv, Op1=tail (bf16). 36.18 MB total.
// ---------------------------------------------------------------------------
extern "C" void kernel_launch(void* const* d_in, const int* in_sizes, int n_in,
                              void* d_out, int out_size, void* d_ws, size_t ws_size,
                              hipStream_t stream) {
  const float* x  = (const float*)d_in[0];
  const float* wq = (const float*)d_in[1];
  const float* wk = (const float*)d_in[2];
  const float* wv = (const float*)d_in[3];
  const float* wo = (const float*)d_in[4];
  float* out = (float*)d_out;

  const size_t XN = (size_t)T_SEQ * C_EMB;      // 3,145,728 elems
  const size_t WN = (size_t)C_EMB * C_EMB;      //   589,824 elems
  unsigned short* base = (unsigned short*)d_ws;

  unsigned short* Xb   = base;
  unsigned short* Wqkv = base + XN;
  unsigned short* Wob  = base + XN + 3 * WN;
  unsigned short* Qb   = base + XN + 4 * WN;
  unsigned short* Kb   = Qb + XN;
  unsigned short* Vt   = Kb + XN;
  unsigned short* tail = Vt + XN;               // byte 29,884,416
  unsigned short* Ob   = Qb;                    // alias: Q dead after attn

  const size_t needA = 29884416ull + 4ull * XN * 4ull + 4ull * NH * T_SEQ * 4ull;  // 81,002,496

  const int ngroups = (int)((XN + 4 * WN) / 4); // 1,376,256
  cast_all_kernel<<<dim3(ngroups / 256), 256, 0, stream>>>(x, wq, wk, wv, wo, Xb);

  gemm_qkv<<<dim3(T_SEQ / 64, 2304 / 128), 256, 0, stream>>>(Xb, Wqkv, Qb, Kb, Vt);

  if (ws_size >= needA) {
    float* Opart4 = (float*)tail;
    float* lpart4 = Opart4 + 4 * XN;
    attn_kernel4<<<dim3((T_SEQ / 128) * 4 * NH), 256, 0, stream>>>(Qb, Kb, Vt, Opart4, lpart4);
    combine_kernel4<<<dim3((int)(XN / 4) / 256), 256, 0, stream>>>(Opart4, lpart4, Ob);
  } else {
    unsigned short* Op0 = base;
    unsigned short* Op1 = tail;
    float* lpart = (float*)(base + XN);
    attn_kernel2<<<dim3((T_SEQ / 128) * 2 * NH), 256, 0, stream>>>(Qb, Kb, Vt, Op0, Op1, lpart);
    combine_kernel2<<<dim3((int)(XN / 4) / 256), 256, 0, stream>>>(Op0, Op1, lpart, Ob);
  }

  gemm_out<<<dim3(T_SEQ / 64, C_EMB / 128), 256, 0, stream>>>(Ob, Wob, out);
}